// Round 2
// baseline (2066.808 us; speedup 1.0000x reference)
//
#include <hip/hip_runtime.h>
#include <cmath>

constexpr int CB = 64;    // batch
constexpr int CN = 1024;  // sentences
constexpr int CM = 1024;  // comments
constexpr int CD = 200;   // feature dim
constexpr int CK = 80;    // attention dim

// ---------------------------------------------------------------- transpose Wl
__global__ __launch_bounds__(256) void k_transpose(const float* __restrict__ Wl,
                                                   float* __restrict__ WlT) {
  int idx = blockIdx.x * 256 + threadIdx.x;
  if (idx < CD * CD) {
    int d = idx / CD, e = idx - d * CD;
    WlT[e * CD + d] = Wl[idx];
  }
}

// ------------------------------------------------- generic row-row (NT) GEMM
// C[b,i,j] = sum_d A[b,i,d] * Bm[b,j,d]   (rows of A dotted with rows of Bm)
// 64x64 block tile, 256 threads, 4x4 per thread, d-chunks of 16, LDS [d][row].
__global__ __launch_bounds__(256) void k_rowrow(
    const float* __restrict__ A, long sA,
    const float* __restrict__ Bm, long sB,
    float* __restrict__ C, long sC, int ldc, int I, int J)
{
  const int bz = blockIdx.z;
  A  += (size_t)bz * sA;
  Bm += (size_t)bz * sB;
  C  += (size_t)bz * sC;
  const int i0 = blockIdx.x * 64, j0 = blockIdx.y * 64;
  __shared__ float As[2][16][68];   // [buf][d][row], pad 68 (16B-aligned rows)
  __shared__ float Bs[2][16][68];
  const int tid = threadIdx.x;
  const int tx = tid & 15, ty = tid >> 4;       // compute map: j = tx*4+, i = ty*4+
  const int lr = tid >> 2, ld4 = (tid & 3) << 2; // staging map
  float acc[4][4] = {};
  for (int ci = 0; ci < 13; ++ci) {
    const int dc = ci * 16;
    const int buf = ci & 1;
    float4 va = make_float4(0.f, 0.f, 0.f, 0.f), vb = va;
    const int gd = dc + ld4;
    if (gd < CD) {
      const int gi = i0 + lr;
      if (gi < I) va = *(const float4*)(A + (size_t)gi * CD + gd);
      const int gj = j0 + lr;
      if (gj < J) vb = *(const float4*)(Bm + (size_t)gj * CD + gd);
    }
    As[buf][ld4 + 0][lr] = va.x; As[buf][ld4 + 1][lr] = va.y;
    As[buf][ld4 + 2][lr] = va.z; As[buf][ld4 + 3][lr] = va.w;
    Bs[buf][ld4 + 0][lr] = vb.x; Bs[buf][ld4 + 1][lr] = vb.y;
    Bs[buf][ld4 + 2][lr] = vb.z; Bs[buf][ld4 + 3][lr] = vb.w;
    __syncthreads();
    #pragma unroll
    for (int dd = 0; dd < 16; ++dd) {
      float4 av = *(const float4*)&As[buf][dd][ty * 4];
      float4 bv = *(const float4*)&Bs[buf][dd][tx * 4];
      acc[0][0] += av.x * bv.x; acc[0][1] += av.x * bv.y; acc[0][2] += av.x * bv.z; acc[0][3] += av.x * bv.w;
      acc[1][0] += av.y * bv.x; acc[1][1] += av.y * bv.y; acc[1][2] += av.y * bv.z; acc[1][3] += av.y * bv.w;
      acc[2][0] += av.z * bv.x; acc[2][1] += av.z * bv.y; acc[2][2] += av.z * bv.z; acc[2][3] += av.z * bv.w;
      acc[3][0] += av.w * bv.x; acc[3][1] += av.w * bv.y; acc[3][2] += av.w * bv.z; acc[3][3] += av.w * bv.w;
    }
  }
  #pragma unroll
  for (int ri = 0; ri < 4; ++ri) {
    const int gi = i0 + ty * 4 + ri;
    const int gj = j0 + tx * 4;
    if (gi < I && gj < J) {
      float4 v; v.x = acc[ri][0]; v.y = acc[ri][1]; v.z = acc[ri][2]; v.w = acc[ri][3];
      *(float4*)(C + (size_t)gi * ldc + gj) = v;
    }
  }
}

// --------------------------------------------------------- fused L + contract
// Per block (j-strip of 32, batch b):
//   Out[k, j0+j] = sum_i W[k,i] * tanh( dot(Arows[i,:], Brows[j0+j,:]) )
// pass1: Arows=CWl (i=m), Brows=sent (j=n), W=WcC -> T1[K,N]
// pass2: Arows=sent (i=n), Brows=CWl (j=m), W=WsS -> T2[K,M]
__global__ __launch_bounds__(256) void k_fused(
    const float* __restrict__ Arows,
    const float* __restrict__ Brows,
    const float* __restrict__ W,
    float* __restrict__ Out)
{
  const int bz = blockIdx.y;
  Arows += (size_t)bz * (CM * CD);
  Brows += (size_t)bz * (CM * CD);
  W     += (size_t)bz * (CK * 1024);
  Out   += (size_t)bz * (CK * 1024);
  const int j0 = blockIdx.x * 32;
  __shared__ float As[2][16][68];  // A chunk [buf][d][i-row]
  __shared__ float Bs[2][16][36];  // B chunk [buf][d][j-row]
  __shared__ float Xs[64][36];     // L tile  [i][j]
  __shared__ float Wt[64][81];     // W tile  [i][k]
  const int tid = threadIdx.x;
  const int tx8 = tid & 7, ty2 = tid >> 3;   // X map: j = tx8*4+, i = ty2*2+
  const int jt = tid & 15, kt = tid >> 4;    // contraction: j = jt*2+, k = kt*5+
  const int lr = tid >> 2, ld4 = (tid & 3) << 2;
  float tacc[5][2] = {};
  for (int it = 0; it < 16; ++it) {
    const int i0 = it * 64;
    // prefetch W tile (80 x 64) into registers early
    float4 wv[5];
    #pragma unroll
    for (int rp = 0; rp < 5; ++rp) {
      const int idx4 = rp * 256 + tid;
      wv[rp] = *(const float4*)(W + (size_t)(idx4 >> 4) * 1024 + i0 + ((idx4 & 15) << 2));
    }
    float xacc[2][4] = {};
    for (int ci = 0; ci < 13; ++ci) {
      const int dc = ci * 16;
      const int buf = ci & 1;
      float4 va = make_float4(0.f, 0.f, 0.f, 0.f), vb = va;
      const int gd = dc + ld4;
      if (gd < CD) {
        va = *(const float4*)(Arows + (size_t)(i0 + lr) * CD + gd);
        if (tid < 128) vb = *(const float4*)(Brows + (size_t)(j0 + lr) * CD + gd);
      }
      As[buf][ld4 + 0][lr] = va.x; As[buf][ld4 + 1][lr] = va.y;
      As[buf][ld4 + 2][lr] = va.z; As[buf][ld4 + 3][lr] = va.w;
      if (tid < 128) {
        Bs[buf][ld4 + 0][lr] = vb.x; Bs[buf][ld4 + 1][lr] = vb.y;
        Bs[buf][ld4 + 2][lr] = vb.z; Bs[buf][ld4 + 3][lr] = vb.w;
      }
      __syncthreads();
      #pragma unroll
      for (int dd = 0; dd < 16; ++dd) {
        float2 av = *(const float2*)&As[buf][dd][ty2 * 2];
        float4 bv = *(const float4*)&Bs[buf][dd][tx8 * 4];
        xacc[0][0] += av.x * bv.x; xacc[0][1] += av.x * bv.y;
        xacc[0][2] += av.x * bv.z; xacc[0][3] += av.x * bv.w;
        xacc[1][0] += av.y * bv.x; xacc[1][1] += av.y * bv.y;
        xacc[1][2] += av.y * bv.z; xacc[1][3] += av.y * bv.w;
      }
    }
    // tanh -> L tile to LDS
    #pragma unroll
    for (int r = 0; r < 2; ++r) {
      float4 v;
      v.x = tanhf(xacc[r][0]); v.y = tanhf(xacc[r][1]);
      v.z = tanhf(xacc[r][2]); v.w = tanhf(xacc[r][3]);
      *(float4*)&Xs[ty2 * 2 + r][tx8 * 4] = v;
    }
    // W tile regs -> LDS (transposed [i][k])
    #pragma unroll
    for (int rp = 0; rp < 5; ++rp) {
      const int idx4 = rp * 256 + tid;
      const int k = idx4 >> 4, i4 = (idx4 & 15) << 2;
      Wt[i4 + 0][k] = wv[rp].x; Wt[i4 + 1][k] = wv[rp].y;
      Wt[i4 + 2][k] = wv[rp].z; Wt[i4 + 3][k] = wv[rp].w;
    }
    __syncthreads();
    // contraction: tacc[k][j] += sum_i Wt[i][k] * Xs[i][j]
    #pragma unroll 8
    for (int i = 0; i < 64; ++i) {
      float2 xv = *(const float2*)&Xs[i][jt * 2];
      #pragma unroll
      for (int c = 0; c < 5; ++c) {
        float w = Wt[i][kt * 5 + c];
        tacc[c][0] += w * xv.x;
        tacc[c][1] += w * xv.y;
      }
    }
    // next iteration's first barrier (after As/Bs write, which contraction
    // doesn't read) orders contraction-reads vs Xs/Wt overwrite.
  }
  #pragma unroll
  for (int c = 0; c < 5; ++c) {
    const int k = kt * 5 + c;
    float2 v; v.x = tacc[c][0]; v.y = tacc[c][1];
    *(float2*)(Out + (size_t)k * 1024 + j0 + jt * 2) = v;
  }
}

// ---------------------------------------------- logits z[side,b,n] over K
__global__ __launch_bounds__(256) void k_logits(
    const float* __restrict__ WsS, const float* __restrict__ T1, const float* __restrict__ whs,
    const float* __restrict__ WcC, const float* __restrict__ T2, const float* __restrict__ whc,
    float* __restrict__ z)
{
  const int side = blockIdx.z, b = blockIdx.y;
  const int n = blockIdx.x * 256 + threadIdx.x;
  const float* P  = side ? WcC : WsS;
  const float* T  = side ? T2 : T1;
  const float* wh = side ? whc : whs;
  const size_t base = (size_t)b * CK * 1024 + n;
  float acc = 0.f;
  #pragma unroll 8
  for (int k = 0; k < CK; ++k)
    acc += wh[k] * tanhf(P[base + (size_t)k * 1024] + T[base + (size_t)k * 1024]);
  z[((size_t)side * CB + b) * 1024 + n] = acc;
}

// ------------------------------------- softmax over BATCH axis (legacy dim=0)
__global__ __launch_bounds__(256) void k_softmax(const float* __restrict__ z,
                                                 float* __restrict__ a) {
  const int idx = blockIdx.x * 256 + threadIdx.x;
  if (idx >= 2 * 1024) return;
  const int side = idx >> 10, n = idx & 1023;
  const float* zc = z + (size_t)side * CB * 1024 + n;
  float mx = -1e30f;
  for (int b = 0; b < CB; ++b) mx = fmaxf(mx, zc[(size_t)b * 1024]);
  float s = 0.f;
  for (int b = 0; b < CB; ++b) s += expf(zc[(size_t)b * 1024] - mx);
  const float inv = 1.0f / s;
  float* ac = a + (size_t)side * CB * 1024 + n;
  for (int b = 0; b < CB; ++b) ac[(size_t)b * 1024] = expf(zc[(size_t)b * 1024] - mx) * inv;
}

// --------------------------------- weighted sum partials: co = rep^T @ weights
__global__ __launch_bounds__(256) void k_wsum(
    const float* __restrict__ sent, const float* __restrict__ comm,
    const float* __restrict__ a, float* __restrict__ partial)
{
  const int t = blockIdx.x, b = blockIdx.y, side = blockIdx.z;
  const int d = threadIdx.x;
  if (d >= CD) return;
  const float* rep = side ? comm : sent;
  const float* aw = a + ((size_t)side * CB + b) * 1024;
  float acc = 0.f;
  const int n0 = t * 128;
  #pragma unroll 4
  for (int n = n0; n < n0 + 128; ++n)
    acc += rep[((size_t)b * 1024 + n) * CD + d] * aw[n];
  partial[(((size_t)side * CB + b) * 8 + t) * CD + d] = acc;
}

__global__ __launch_bounds__(256) void k_reduce(const float* __restrict__ partial,
                                                float* __restrict__ out) {
  const int idx = blockIdx.x * 256 + threadIdx.x;
  if (idx < CB * 2 * CD) {
    const int b = idx / 400, r = idx % 400;
    const int side = r / CD, d = r - side * CD;
    const float* p = partial + (((size_t)side * CB + b) * 8) * CD + d;
    float s = 0.f;
    #pragma unroll
    for (int t = 0; t < 8; ++t) s += p[t * CD];
    out[idx] = s;
  }
}

extern "C" void kernel_launch(void* const* d_in, const int* in_sizes, int n_in,
                              void* d_out, int out_size, void* d_ws, size_t ws_size,
                              hipStream_t stream) {
  (void)in_sizes; (void)n_in; (void)out_size; (void)ws_size;
  const float* sent = (const float*)d_in[0];   // [B,N,D]
  const float* comm = (const float*)d_in[1];   // [B,M,D]
  const float* Wl   = (const float*)d_in[2];   // [D,D]
  const float* Wc   = (const float*)d_in[3];   // [K,D]
  const float* Ws   = (const float*)d_in[4];   // [K,D]
  const float* whs  = (const float*)d_in[5];   // [1,K]
  const float* whc  = (const float*)d_in[6];   // [1,K]
  float* out = (float*)d_out;

  float* ws      = (float*)d_ws;
  float* WlT     = ws;                     //    40,000
  float* CWl     = WlT + 40000;            // 13,107,200  (comment @ Wl)
  float* WsS     = CWl + 13107200;         //  5,242,880  [B,K,N]
  float* WcC     = WsS + 5242880;          //  5,242,880  [B,K,M]
  float* T1      = WcC + 5242880;          //  5,242,880  [B,K,N]
  float* T2      = T1  + 5242880;          //  5,242,880  [B,K,M]
  float* z       = T2  + 5242880;          //    131,072  [2,B,1024]
  float* a       = z   + 131072;           //    131,072
  float* partial = a   + 131072;           //    204,800
  // total ~34.6M floats = 138.3 MB

  k_transpose<<<dim3(157), 256, 0, stream>>>(Wl, WlT);
  // CWl[r,e] = comment[r,:] . WlT[e,:]   (single "batch")
  k_rowrow<<<dim3(1024, 4, 1), 256, 0, stream>>>(comm, 0L, WlT, 0L,
                                                 CWl, 0L, CD, CB * CM, CD);
  // WsS[b,k,n] = Ws[k,:] . sent[b,n,:]
  k_rowrow<<<dim3(2, 16, CB), 256, 0, stream>>>(Ws, 0L, sent, (long)CN * CD,
                                                WsS, (long)CK * 1024, 1024, CK, CN);
  // WcC[b,k,m] = Wc[k,:] . comm[b,m,:]
  k_rowrow<<<dim3(2, 16, CB), 256, 0, stream>>>(Wc, 0L, comm, (long)CM * CD,
                                                WcC, (long)CK * 1024, 1024, CK, CM);
  // T1[b,k,n] = sum_m WcC[b,k,m] * tanh(CWl[b,m,:] . sent[b,n,:])
  k_fused<<<dim3(32, CB), 256, 0, stream>>>(CWl, sent, WcC, T1);
  // T2[b,k,m] = sum_n WsS[b,k,n] * tanh(sent[b,n,:] . CWl[b,m,:])
  k_fused<<<dim3(32, CB), 256, 0, stream>>>(sent, CWl, WsS, T2);
  k_logits<<<dim3(4, CB, 2), 256, 0, stream>>>(WsS, T1, whs, WcC, T2, whc, z);
  k_softmax<<<dim3(8), 256, 0, stream>>>(z, a);
  k_wsum<<<dim3(8, CB, 2), 256, 0, stream>>>(sent, comm, a, partial);
  k_reduce<<<dim3(100), 256, 0, stream>>>(partial, out);
}

// Round 7
// 1996.457 us; speedup vs baseline: 1.0352x; 1.0352x over previous
//
#include <hip/hip_runtime.h>
#include <cmath>

constexpr int CB = 64;    // batch
constexpr int CN = 1024;  // sentences
constexpr int CM = 1024;  // comments
constexpr int CD = 200;   // feature dim
constexpr int CK = 80;    // attention dim

typedef short  s16x8  __attribute__((ext_vector_type(8)));
typedef unsigned short u16x8v __attribute__((ext_vector_type(8)));
typedef unsigned short u16x4v __attribute__((ext_vector_type(4)));
typedef float  f32x4  __attribute__((ext_vector_type(4)));

// Padded-stride LDS layouts (byte offsets). Bijective by construction.
// A/B planes: 64 rows x 64B data, stride 80B  (20 words mod 32 -> uniform 8-slot banking)
// T/W planes: rows x 128B data,  stride 144B (36 words mod 32 -> uniform 8-slot banking)
#define AOFF(row, byteoff) ((row) * 80  + (byteoff))
#define TOFF(row, byteoff) ((row) * 144 + (byteoff))
#define WOFF(row, byteoff) ((row) * 144 + (byteoff))

__device__ inline unsigned short bf16_rtne(float x) {
  unsigned u = __float_as_uint(x);
  unsigned r = u + 0x7FFFu + ((u >> 16) & 1u);
  return (unsigned short)(r >> 16);
}
__device__ inline float bf16_to_f(unsigned short h) {
  return __uint_as_float((unsigned)h << 16);
}
// fp32 -> (hi, lo) bf16 pair: x ~= hi + lo to ~2^-18 relative.
__device__ inline void split2(float x, unsigned short& h, unsigned short& l) {
  h = bf16_rtne(x);
  l = bf16_rtne(x - bf16_to_f(h));
}
__device__ inline float f4e(const float4& v, int e) {
  return e == 0 ? v.x : e == 1 ? v.y : e == 2 ? v.z : v.w;
}
__device__ inline f32x4 mfma16(s16x8 a, s16x8 b, f32x4 c) {
  return __builtin_amdgcn_mfma_f32_16x16x32_bf16(a, b, c, 0, 0, 0);
}

// ---------------------------------------------------------------- transpose Wl
__global__ __launch_bounds__(256) void k_transpose(const float* __restrict__ Wl,
                                                   float* __restrict__ WlT) {
  int idx = blockIdx.x * 256 + threadIdx.x;
  if (idx < CD * CD) {
    int d = idx / CD, e = idx - d * CD;
    WlT[e * CD + d] = Wl[idx];
  }
}

// ------------------------------------------------- generic row-row (NT) GEMM
__global__ __launch_bounds__(256) void k_rowrow(
    const float* __restrict__ A, long sA,
    const float* __restrict__ Bm, long sB,
    float* __restrict__ C, long sC, int ldc, int I, int J)
{
  const int bz = blockIdx.z;
  A  += (size_t)bz * sA;
  Bm += (size_t)bz * sB;
  C  += (size_t)bz * sC;
  const int i0 = blockIdx.x * 64, j0 = blockIdx.y * 64;
  __shared__ float As[2][16][68];
  __shared__ float Bs[2][16][68];
  const int tid = threadIdx.x;
  const int tx = tid & 15, ty = tid >> 4;
  const int lr = tid >> 2, ld4 = (tid & 3) << 2;
  float acc[4][4] = {};
  for (int ci = 0; ci < 13; ++ci) {
    const int dc = ci * 16;
    const int buf = ci & 1;
    float4 va = make_float4(0.f, 0.f, 0.f, 0.f), vb = va;
    const int gd = dc + ld4;
    if (gd < CD) {
      const int gi = i0 + lr;
      if (gi < I) va = *(const float4*)(A + (size_t)gi * CD + gd);
      const int gj = j0 + lr;
      if (gj < J) vb = *(const float4*)(Bm + (size_t)gj * CD + gd);
    }
    As[buf][ld4 + 0][lr] = va.x; As[buf][ld4 + 1][lr] = va.y;
    As[buf][ld4 + 2][lr] = va.z; As[buf][ld4 + 3][lr] = va.w;
    Bs[buf][ld4 + 0][lr] = vb.x; Bs[buf][ld4 + 1][lr] = vb.y;
    Bs[buf][ld4 + 2][lr] = vb.z; Bs[buf][ld4 + 3][lr] = vb.w;
    __syncthreads();
    #pragma unroll
    for (int dd = 0; dd < 16; ++dd) {
      float4 av = *(const float4*)&As[buf][dd][ty * 4];
      float4 bv = *(const float4*)&Bs[buf][dd][tx * 4];
      acc[0][0] += av.x * bv.x; acc[0][1] += av.x * bv.y; acc[0][2] += av.x * bv.z; acc[0][3] += av.x * bv.w;
      acc[1][0] += av.y * bv.x; acc[1][1] += av.y * bv.y; acc[1][2] += av.y * bv.z; acc[1][3] += av.y * bv.w;
      acc[2][0] += av.z * bv.x; acc[2][1] += av.z * bv.y; acc[2][2] += av.z * bv.z; acc[2][3] += av.z * bv.w;
      acc[3][0] += av.w * bv.x; acc[3][1] += av.w * bv.y; acc[3][2] += av.w * bv.z; acc[3][3] += av.w * bv.w;
    }
  }
  #pragma unroll
  for (int ri = 0; ri < 4; ++ri) {
    const int gi = i0 + ty * 4 + ri;
    const int gj = j0 + tx * 4;
    if (gi < I && gj < J) {
      float4 v; v.x = acc[ri][0]; v.y = acc[ri][1]; v.z = acc[ri][2]; v.w = acc[ri][3];
      *(float4*)(C + (size_t)gi * ldc + gj) = v;
    }
  }
}

// --------------------------------------------- fused L + contract, MFMA path
// Per block (batch bz, j-strip of 64):
//   Out[k, j0+j] = sum_i W[k,i] * tanh( dot(Arows[i,:], Brows[j0+j,:]) )
// X-GEMM and the i-contraction both run on split-bf16 MFMA (3-term hi/lo).
__global__ __launch_bounds__(256, 2) void k_fused_mfma(
    const float* __restrict__ Arows,
    const float* __restrict__ Brows,
    const float* __restrict__ W,
    float* __restrict__ Out)
{
  const int bz = blockIdx.y;
  Arows += (size_t)bz * (CM * CD);
  Brows += (size_t)bz * (CM * CD);
  W     += (size_t)bz * (CK * 1024);
  Out   += (size_t)bz * (CK * 1024);
  const int j0 = blockIdx.x * 64;

  // bf16 planes, padded strides (byte-addressed via macros)
  __shared__ __align__(16) unsigned short sAh[2560], sAl[2560];  // [64 i][32 d], 80B rows
  __shared__ __align__(16) unsigned short sBh[2560], sBl[2560];  // [64 j][32 d], 80B rows
  __shared__ __align__(16) unsigned short sTh[4608], sTl[4608];  // [64 n][64 i], 144B rows
  __shared__ __align__(16) unsigned short sWh[5760], sWl[5760];  // [80 k][64 i], 144B rows

  const int tid = threadIdx.x;
  const int lane = tid & 63, wid = tid >> 6;
  const int l15 = lane & 15, l4 = lane >> 4;    // MFMA lane decomposition
  const int ti = wid >> 1, tj = wid & 1;        // X-phase: wave's 32x32 quadrant
  const int nc = wid;                           // contraction: wave's n-col group
  const int srow = tid & 63, sd8 = (tid >> 6) << 3;  // staging map (row, d-slot)

  const float* brow = Brows + (size_t)(j0 + srow) * CD;

  f32x4 tacc[5];
  #pragma unroll
  for (int q = 0; q < 5; ++q) tacc[q] = (f32x4){0.f, 0.f, 0.f, 0.f};

  for (int it = 0; it < 16; ++it) {
    const int i0 = it * 64;
    const float* arow = Arows + (size_t)(i0 + srow) * CD;

    f32x4 xacc[2][2];
    #pragma unroll
    for (int ih = 0; ih < 2; ++ih)
      #pragma unroll
      for (int jh = 0; jh < 2; ++jh) xacc[ih][jh] = (f32x4){0.f, 0.f, 0.f, 0.f};

    // prologue: load chunk 0 (d = sd8..sd8+7, all < 200)
    float4 a0, a1, b0, b1;
    {
      const int gd = sd8;
      a0 = *(const float4*)(arow + gd);  a1 = *(const float4*)(arow + gd + 4);
      b0 = *(const float4*)(brow + gd);  b1 = *(const float4*)(brow + gd + 4);
    }
    #pragma unroll 1
    for (int ci = 0; ci < 7; ++ci) {
      // convert + write staged chunk to LDS
      {
        u16x8v ah, al, bh, bl;
        #pragma unroll
        for (int e = 0; e < 4; ++e) {
          unsigned short h, l;
          split2(f4e(a0, e), h, l); ah[e] = h; al[e] = l;
          split2(f4e(b0, e), h, l); bh[e] = h; bl[e] = l;
        }
        #pragma unroll
        for (int e = 0; e < 4; ++e) {
          unsigned short h, l;
          split2(f4e(a1, e), h, l); ah[e + 4] = h; al[e + 4] = l;
          split2(f4e(b1, e), h, l); bh[e + 4] = h; bl[e + 4] = l;
        }
        const int sb = AOFF(srow, sd8 * 2);
        *(u16x8v*)((char*)sAh + sb) = ah;
        *(u16x8v*)((char*)sAl + sb) = al;
        *(u16x8v*)((char*)sBh + sb) = bh;
        *(u16x8v*)((char*)sBl + sb) = bl;
      }
      __syncthreads();
      // prefetch next chunk (overlaps with MFMA below)
      if (ci < 6) {
        const int gd = (ci + 1) * 32 + sd8;
        float4 z = make_float4(0.f, 0.f, 0.f, 0.f);
        a0 = (gd + 4 <= CD) ? *(const float4*)(arow + gd)     : z;
        a1 = (gd + 8 <= CD) ? *(const float4*)(arow + gd + 4) : z;
        b0 = (gd + 4 <= CD) ? *(const float4*)(brow + gd)     : z;
        b1 = (gd + 8 <= CD) ? *(const float4*)(brow + gd + 4) : z;
      }
      // X MFMA on current chunk
      {
        s16x8 fA[2][2], fB[2][2];
        #pragma unroll
        for (int h = 0; h < 2; ++h) {
          const int ab = AOFF(ti * 32 + h * 16 + l15, l4 * 16);
          fA[h][0] = *(const s16x8*)((const char*)sAh + ab);
          fA[h][1] = *(const s16x8*)((const char*)sAl + ab);
          const int bb = AOFF(tj * 32 + h * 16 + l15, l4 * 16);
          fB[h][0] = *(const s16x8*)((const char*)sBh + bb);
          fB[h][1] = *(const s16x8*)((const char*)sBl + bb);
        }
        #pragma unroll
        for (int ih = 0; ih < 2; ++ih)
          #pragma unroll
          for (int jh = 0; jh < 2; ++jh) {
            xacc[ih][jh] = mfma16(fA[ih][0], fB[jh][0], xacc[ih][jh]);
            xacc[ih][jh] = mfma16(fA[ih][0], fB[jh][1], xacc[ih][jh]);
            xacc[ih][jh] = mfma16(fA[ih][1], fB[jh][0], xacc[ih][jh]);
          }
      }
      __syncthreads();
    }

    // tanh -> t (hi/lo bf16), stored [n][i] so contraction frags are row-reads.
    // C/D layout (m89): col(n) = lane&15, row(i) = (lane>>4)*4 + reg.
    #pragma unroll
    for (int ih = 0; ih < 2; ++ih)
      #pragma unroll
      for (int jh = 0; jh < 2; ++jh) {
        const int n  = tj * 32 + jh * 16 + l15;
        const int ii = ti * 32 + ih * 16 + l4 * 4;
        u16x4v th, tl;
        #pragma unroll
        for (int r = 0; r < 4; ++r) {
          float x = tanhf(xacc[ih][jh][r]);
          unsigned short h, l; split2(x, h, l);
          th[r] = h; tl[r] = l;
        }
        const int tb = TOFF(n, ii * 2);
        *(u16x4v*)((char*)sTh + tb) = th;
        *(u16x4v*)((char*)sTl + tb) = tl;
      }

    // stage W tile (80 x 64) fp32 -> hi/lo
    for (int u = tid; u < 640; u += 256) {
      const int k = u >> 3, i8 = (u & 7) << 3;
      const float* wp = W + (size_t)k * 1024 + i0 + i8;
      float4 w0 = *(const float4*)wp, w1 = *(const float4*)(wp + 4);
      u16x8v wh, wl;
      #pragma unroll
      for (int e = 0; e < 4; ++e) {
        unsigned short h, l;
        split2(f4e(w0, e), h, l); wh[e] = h; wl[e] = l;
      }
      #pragma unroll
      for (int e = 0; e < 4; ++e) {
        unsigned short h, l;
        split2(f4e(w1, e), h, l); wh[e + 4] = h; wl[e + 4] = l;
      }
      const int wb = WOFF(k, i8 * 2);
      *(u16x8v*)((char*)sWh + wb) = wh;
      *(u16x8v*)((char*)sWl + wb) = wl;
    }
    __syncthreads();

    // contraction MFMA: tacc[kr] += W(80 x 64i) x t(64i x 64n), k-dim = i
    #pragma unroll
    for (int ks = 0; ks < 2; ++ks) {
      const int tb = TOFF(nc * 16 + l15, ks * 64 + l4 * 16);
      s16x8 fth = *(const s16x8*)((const char*)sTh + tb);
      s16x8 ftl = *(const s16x8*)((const char*)sTl + tb);
      #pragma unroll
      for (int kr = 0; kr < 5; ++kr) {
        const int wb = WOFF(kr * 16 + l15, ks * 64 + l4 * 16);
        s16x8 fwh = *(const s16x8*)((const char*)sWh + wb);
        s16x8 fwl = *(const s16x8*)((const char*)sWl + wb);
        tacc[kr] = mfma16(fwh, fth, tacc[kr]);
        tacc[kr] = mfma16(fwh, ftl, tacc[kr]);
        tacc[kr] = mfma16(fwl, fth, tacc[kr]);
      }
    }
    // no trailing barrier needed: next-iteration staging touches only sA*/sB*,
    // and the ci=0 barrier orders those writes; sT/sW are next written >=14
    // barriers later (after the full chunk loop).
  }

  // epilogue: Out[k, j0+n]; C/D: col(n)=lane&15, row(k)=(lane>>4)*4+reg
  #pragma unroll
  for (int kr = 0; kr < 5; ++kr)
    #pragma unroll
    for (int r = 0; r < 4; ++r) {
      const int k = kr * 16 + l4 * 4 + r;
      Out[(size_t)k * 1024 + j0 + nc * 16 + l15] = tacc[kr][r];
    }
}

// ---------------------------------------------- logits z[side,b,n] over K
__global__ __launch_bounds__(256) void k_logits(
    const float* __restrict__ WsS, const float* __restrict__ T1, const float* __restrict__ whs,
    const float* __restrict__ WcC, const float* __restrict__ T2, const float* __restrict__ whc,
    float* __restrict__ z)
{
  const int side = blockIdx.z, b = blockIdx.y;
  const int n = blockIdx.x * 256 + threadIdx.x;
  const float* P  = side ? WcC : WsS;
  const float* T  = side ? T2 : T1;
  const float* wh = side ? whc : whs;
  const size_t base = (size_t)b * CK * 1024 + n;
  float acc = 0.f;
  #pragma unroll 8
  for (int k = 0; k < CK; ++k)
    acc += wh[k] * tanhf(P[base + (size_t)k * 1024] + T[base + (size_t)k * 1024]);
  z[((size_t)side * CB + b) * 1024 + n] = acc;
}

// ------------------------------------- softmax over BATCH axis (legacy dim=0)
__global__ __launch_bounds__(256) void k_softmax(const float* __restrict__ z,
                                                 float* __restrict__ a) {
  const int idx = blockIdx.x * 256 + threadIdx.x;
  if (idx >= 2 * 1024) return;
  const int side = idx >> 10, n = idx & 1023;
  const float* zc = z + (size_t)side * CB * 1024 + n;
  float mx = -1e30f;
  for (int b = 0; b < CB; ++b) mx = fmaxf(mx, zc[(size_t)b * 1024]);
  float s = 0.f;
  for (int b = 0; b < CB; ++b) s += expf(zc[(size_t)b * 1024] - mx);
  const float inv = 1.0f / s;
  float* ac = a + (size_t)side * CB * 1024 + n;
  for (int b = 0; b < CB; ++b) ac[(size_t)b * 1024] = expf(zc[(size_t)b * 1024] - mx) * inv;
}

// --------------------------------- weighted sum partials: co = rep^T @ weights
__global__ __launch_bounds__(256) void k_wsum(
    const float* __restrict__ sent, const float* __restrict__ comm,
    const float* __restrict__ a, float* __restrict__ partial)
{
  const int t = blockIdx.x, b = blockIdx.y, side = blockIdx.z;
  const int d = threadIdx.x;
  if (d >= CD) return;
  const float* rep = side ? comm : sent;
  const float* aw = a + ((size_t)side * CB + b) * 1024;
  float acc = 0.f;
  const int n0 = t * 128;
  #pragma unroll 4
  for (int n = n0; n < n0 + 128; ++n)
    acc += rep[((size_t)b * 1024 + n) * CD + d] * aw[n];
  partial[(((size_t)side * CB + b) * 8 + t) * CD + d] = acc;
}

__global__ __launch_bounds__(256) void k_reduce(const float* __restrict__ partial,
                                                float* __restrict__ out) {
  const int idx = blockIdx.x * 256 + threadIdx.x;
  if (idx < CB * 2 * CD) {
    const int b = idx / 400, r = idx % 400;
    const int side = r / CD, d = r - side * CD;
    const float* p = partial + (((size_t)side * CB + b) * 8) * CD + d;
    float s = 0.f;
    #pragma unroll
    for (int t = 0; t < 8; ++t) s += p[t * CD];
    out[idx] = s;
  }
}

extern "C" void kernel_launch(void* const* d_in, const int* in_sizes, int n_in,
                              void* d_out, int out_size, void* d_ws, size_t ws_size,
                              hipStream_t stream) {
  (void)in_sizes; (void)n_in; (void)out_size; (void)ws_size;
  const float* sent = (const float*)d_in[0];   // [B,N,D]
  const float* comm = (const float*)d_in[1];   // [B,M,D]
  const float* Wl   = (const float*)d_in[2];   // [D,D]
  const float* Wc   = (const float*)d_in[3];   // [K,D]
  const float* Ws   = (const float*)d_in[4];   // [K,D]
  const float* whs  = (const float*)d_in[5];   // [1,K]
  const float* whc  = (const float*)d_in[6];   // [1,K]
  float* out = (float*)d_out;

  float* ws      = (float*)d_ws;
  float* WlT     = ws;                     //    40,000
  float* CWl     = WlT + 40000;            // 13,107,200  (comment @ Wl)
  float* WsS     = CWl + 13107200;         //  5,242,880  [B,K,N]
  float* WcC     = WsS + 5242880;          //  5,242,880  [B,K,M]
  float* T1      = WcC + 5242880;          //  5,242,880  [B,K,N]
  float* T2      = T1  + 5242880;          //  5,242,880  [B,K,M]
  float* z       = T2  + 5242880;          //    131,072  [2,B,1024]
  float* a       = z   + 131072;           //    131,072
  float* partial = a   + 131072;           //    204,800
  // total ~34.6M floats = 138.3 MB

  k_transpose<<<dim3(157), 256, 0, stream>>>(Wl, WlT);
  // CWl[r,e] = comment[r,:] . WlT[e,:]   (single "batch")
  k_rowrow<<<dim3(1024, 4, 1), 256, 0, stream>>>(comm, 0L, WlT, 0L,
                                                 CWl, 0L, CD, CB * CM, CD);
  // WsS[b,k,n] = Ws[k,:] . sent[b,n,:]
  k_rowrow<<<dim3(2, 16, CB), 256, 0, stream>>>(Ws, 0L, sent, (long)CN * CD,
                                                WsS, (long)CK * 1024, 1024, CK, CN);
  // WcC[b,k,m] = Wc[k,:] . comm[b,m,:]
  k_rowrow<<<dim3(2, 16, CB), 256, 0, stream>>>(Wc, 0L, comm, (long)CM * CD,
                                                WcC, (long)CK * 1024, 1024, CK, CM);
  // T1[b,k,n] = sum_m WcC[b,k,m] * tanh(CWl[b,m,:] . sent[b,n,:])
  k_fused_mfma<<<dim3(16, CB), 256, 0, stream>>>(CWl, sent, WcC, T1);
  // T2[b,k,m] = sum_n WsS[b,k,n] * tanh(sent[b,n,:] . CWl[b,m,:])
  k_fused_mfma<<<dim3(16, CB), 256, 0, stream>>>(sent, CWl, WsS, T2);
  k_logits<<<dim3(4, CB, 2), 256, 0, stream>>>(WsS, T1, whs, WcC, T2, whc, z);
  k_softmax<<<dim3(8), 256, 0, stream>>>(z, a);
  k_wsum<<<dim3(8, CB, 2), 256, 0, stream>>>(sent, comm, a, partial);
  k_reduce<<<dim3(100), 256, 0, stream>>>(partial, out);
}